// Round 9
// baseline (223.055 us; speedup 1.0000x reference)
//
#include <hip/hip_runtime.h>
#include <math.h>

#define B_ 64
#define F_ 32
#define S_ 512
#define P_ 96
#define E_ 8
#define H_ 2048
#define M_ 2048   // B_*F_ rows, m = b*F_ + f

#define BM 128
#define BH 128
#define ZSPLIT 4
#define HPZ (H_ / ZSPLIT)   // 512 h per z-block
#define NHT (HPZ / BH)      // 4 h-chunks per block
#define NKC (S_ / 64)       // 8 k-chunks of 64
#define HPITCH 136          // 128 + 8 skew (bf16)
#define W1SCALE 8.0f
#define TSTRIDE 8192        // bytes per fp8 frag-tile: 64 ksegs x 16 lanes x 8 B

typedef __bf16 bf16x8 __attribute__((ext_vector_type(8)));
typedef __bf16 bf16x4 __attribute__((ext_vector_type(4)));
typedef float f32x4 __attribute__((ext_vector_type(4)));
typedef unsigned char u8;
typedef int i32x2 __attribute__((ext_vector_type(2)));
typedef int i32x4 __attribute__((ext_vector_type(4)));

#define MFMA16(a, b, c) __builtin_amdgcn_mfma_f32_16x16x32_bf16((a), (b), (c), 0, 0, 0)
#define MFMA8(a, b, c) __builtin_amdgcn_mfma_f32_16x16x32_fp8_fp8((a), (b), (c), 0, 0, 0)

__device__ __forceinline__ int pk_fp8x4(float a, float b, float c, float d) {
  int v = __builtin_amdgcn_cvt_pk_fp8_f32(a, b, 0, false);
  return __builtin_amdgcn_cvt_pk_fp8_f32(c, d, v, true);
}

__device__ __forceinline__ float fast_gelu(float x) {
  float e = __builtin_amdgcn_exp2f(-2.45546696f * x);
  return x * __builtin_amdgcn_rcpf(1.0f + e);
}

// =================== k_prep_w1 (256 threads, 256 blocks) ===================
// W1 [E][S][H] f32 -> w1q fp8 frag-order [e][h>>4][s>>3][h&15][8B], x W1SCALE.
__global__ __launch_bounds__(256) void k_prep_w1(const float* __restrict__ W1,
                                                 u8* __restrict__ w1q) {
  __shared__ __align__(16) __bf16 btile[256 * 68];   // [s][h] 34,816 B
  const int tid = threadIdx.x;
  const int e = blockIdx.x >> 5, hstrip = blockIdx.x & 31;
  const float* src = W1 + (size_t)e * S_ * H_ + hstrip * 64;
#pragma unroll
  for (int pass = 0; pass < 2; ++pass) {
    {
      int rb = tid >> 2;
      int hseg = (tid & 3) * 16;
#pragma unroll
      for (int it = 0; it < 4; ++it) {
        int r = it * 64 + rb;
        const float* srow = src + (size_t)(pass * 256 + r) * H_ + hseg;
#pragma unroll
        for (int k = 0; k < 4; ++k) {
          f32x4 v = *(const f32x4*)(srow + k * 4);
          bf16x4 o = {(__bf16)v[0], (__bf16)v[1], (__bf16)v[2], (__bf16)v[3]};
          *(bf16x4*)&btile[r * 68 + hseg + k * 4] = o;
        }
      }
    }
    __syncthreads();
#pragma unroll
    for (int i = 0; i < 4; ++i) {
      int c = tid + 256 * i;
      int tloc = c >> 8, rem = c & 255;
      int gloc = rem >> 3, u = rem & 7;
      int htile = hstrip * 4 + tloc;
      int g = pass * 32 + gloc;
      float v[16];
#pragma unroll
      for (int rr = 0; rr < 2; ++rr)
#pragma unroll
        for (int j = 0; j < 8; ++j)
          v[rr * 8 + j] = W1SCALE * (float)btile[(gloc * 8 + j) * 68 + tloc * 16 + 2 * u + rr];
      i32x4 o = {pk_fp8x4(v[0], v[1], v[2], v[3]),   pk_fp8x4(v[4], v[5], v[6], v[7]),
                 pk_fp8x4(v[8], v[9], v[10], v[11]), pk_fp8x4(v[12], v[13], v[14], v[15])};
      *(i32x4*)(w1q + ((size_t)(e * 128 + htile) * 64 + g) * 128 + u * 16) = o;
    }
    __syncthreads();
  }
}

// =================== k_prep_rest (256 threads, 1280 blocks) ===================
// [0,256):    W2 [E][H][P] f32 -> w2f bf16 frag-order [(e*6+pt)*256+kseg][l15][8]
// [256,768):  x [M][S] f32 -> xq fp8 frag-order [m>>4][s>>3][m&15][8B]
// [768,1280): gates
__global__ __launch_bounds__(256) void k_prep_rest(const float* __restrict__ x,
                                                   const float* __restrict__ te,
                                                   const float* __restrict__ Wg,
                                                   const float* __restrict__ bg,
                                                   const float* __restrict__ W2,
                                                   u8* __restrict__ xq,
                                                   __bf16* __restrict__ w2f,
                                                   float* __restrict__ gates) {
  __shared__ float t2[64 * 97];   // [h][p] 24.8 KB
  const int blk = blockIdx.x;
  const int tid = threadIdx.x;

  if (blk < 256) {                        // ---- W2 frag-pack: (e, 64-h block)
    int e = blk >> 5, hblk = blk & 31;
    const float* src = W2 + (size_t)e * H_ * P_ + (size_t)(hblk * 64) * P_;
    {
      int h = tid >> 2;
      int pseg = (tid & 3) * 24;
#pragma unroll
      for (int k = 0; k < 6; ++k) {
        f32x4 v = *(const f32x4*)(src + (size_t)h * P_ + pseg + k * 4);
#pragma unroll
        for (int u = 0; u < 4; ++u) t2[h * 97 + pseg + k * 4 + u] = v[u];
      }
    }
    __syncthreads();
#pragma unroll
    for (int i = 0; i < 3; ++i) {         // 768 chunks of 16 B
      int c = tid + 256 * i;
      int l15 = c & 15, r = c >> 4;
      int ksl = r & 7, pt = r >> 3;       // kseg-local, p-tile
      bf16x8 o;
#pragma unroll
      for (int d = 0; d < 8; ++d)
        o[d] = (__bf16)t2[(ksl * 8 + d) * 97 + pt * 16 + l15];
      *(bf16x8*)(w2f + ((size_t)((e * 6 + pt) * 256 + hblk * 8 + ksl)) * 128 + l15 * 8) = o;
    }
    return;
  }
  if (blk < 768) {                        // ---- x -> fp8 frag-order
    int t = blk - 256;
    int mtile = t >> 2, gq = t & 3;
    int ml = tid & 15, gloc = tid >> 4;
    int g = gq * 16 + gloc;
    const float* srow = x + (size_t)(mtile * 16 + ml) * S_ + g * 8;
    f32x4 a = *(const f32x4*)srow;
    f32x4 b = *(const f32x4*)(srow + 4);
    i32x2 o = {pk_fp8x4(a[0], a[1], a[2], a[3]), pk_fp8x4(b[0], b[1], b[2], b[3])};
    *(i32x2*)(xq + ((size_t)(mtile * 64 + g)) * 128 + ml * 8) = o;
    return;
  }
  // ---- gates: one wave per row m
  int wave = tid >> 6, lane = tid & 63;
  int m = (blk - 768) * 4 + wave;
  const float* trow = te + (size_t)m * S_;
  float acc[E_];
#pragma unroll
  for (int e = 0; e < E_; ++e) acc[e] = 0.f;
  for (int s = lane; s < S_; s += 64) {
    float t = trow[s];
    const f32x4* wgr = (const f32x4*)(Wg + s * E_);
    f32x4 a = wgr[0], b = wgr[1];
    acc[0] += t * a[0]; acc[1] += t * a[1]; acc[2] += t * a[2]; acc[3] += t * a[3];
    acc[4] += t * b[0]; acc[5] += t * b[1]; acc[6] += t * b[2]; acc[7] += t * b[3];
  }
#pragma unroll
  for (int e = 0; e < E_; ++e) {
#pragma unroll
    for (int off = 32; off > 0; off >>= 1) acc[e] += __shfl_xor(acc[e], off, 64);
  }
  if (lane == 0) {
    float lg[E_];
    float m1 = -3.4e38f, m2 = -3.4e38f;
#pragma unroll
    for (int e = 0; e < E_; ++e) {
      float v = acc[e] + bg[e];
      lg[e] = v;
      if (v > m1) { m2 = m1; m1 = v; }
      else if (v > m2) { m2 = v; }
    }
    float den = 0.f, sm[E_];
#pragma unroll
    for (int e = 0; e < E_; ++e) { sm[e] = expf(lg[e] - m1); den += sm[e]; }
    float inv = 1.f / den;
    float dmax = -3.4e38f, dec[E_];
#pragma unroll
    for (int e = 0; e < E_; ++e) {
      float p = sm[e] * inv;
      float d = (lg[e] < m2) ? (10.f * logf(p + 1.f)) : (10.f * (expf(p) - 1.f));
      dec[e] = d;
      dmax = fmaxf(dmax, d);
    }
    float dden = 0.f;
#pragma unroll
    for (int e = 0; e < E_; ++e) { dec[e] = expf(dec[e] - dmax); dden += dec[e]; }
    float dinv = 1.f / dden;
#pragma unroll
    for (int e = 0; e < E_; ++e) gates[m * E_ + e] = dec[e] * dinv;
  }
}

// =================== k_experts: grid (E_, 16, ZSPLIT+1), 512 threads ===================
// GEMM1: LDS-free, frag-order direct loads, MANUAL 1-kc software pipeline
// (ping-pong reg arrays, fully unrolled) so vmcnt never drains mid-loop.
// GEMM2: frag-packed w2f (contiguous 1 KB wave loads), kk-pipelined, kk0
// prefetched before the gelu barrier. Only LDS = Hs (34.8 KB) -> 2 blocks/CU.
__global__ __launch_bounds__(512, 4) void k_experts(
    const u8* __restrict__ xq,        // fp8 frag-order
    const u8* __restrict__ w1q,       // fp8 frag-order, x W1SCALE
    const __bf16* __restrict__ w2f,   // bf16 frag-order
    const float* __restrict__ b1,     // [E][H]
    const float* __restrict__ b2,     // [E][P]
    const float* __restrict__ gates,  // [M][E]
    float* __restrict__ out)          // [M][P] (+2 loss slots)
{
  __shared__ __align__(16) __bf16 Hs[BM * HPITCH];   // 34.8 KB

  const int tid = threadIdx.x;

  if (blockIdx.z == ZSPLIT) {      // ---- loss block (others exit)
    if (blockIdx.x != 0 || blockIdx.y != 0) return;
    float* gsum = (float*)&Hs[0];
    float* cvs  = gsum + F_ * E_;
    float* ents = cvs + F_;
    if (tid < 256) {
      int f = tid >> 3, e = tid & 7;
      float s = 0.f;
      for (int b = 0; b < B_; ++b) s += gates[(size_t)(b * F_ + f) * E_ + e];
      gsum[f * E_ + e] = s;
    }
    __syncthreads();
    if (tid < F_) {
      float mean = 0.f;
#pragma unroll
      for (int k = 0; k < E_; ++k) mean += gsum[tid * E_ + k];
      mean *= (1.f / E_);
      float ss = 0.f;
#pragma unroll
      for (int k = 0; k < E_; ++k) { float d = gsum[tid * E_ + k] - mean; ss += d * d; }
      float var = (float)P_ * ss / (float)(E_ * P_ - 1);
      cvs[tid] = var / (mean * mean + 1e-10f);
      float ent = 0.f;
#pragma unroll
      for (int k = 0; k < E_; ++k) { float g = gsum[tid * E_ + k] * (1.f / B_); ent += -g * logf(g + 1e-8f); }
      ents[tid] = ent * (1.f / E_);
    }
    __syncthreads();
    if (tid == 0) {
      float a = 0.f, b = 0.f;
      for (int k = 0; k < F_; ++k) { a += cvs[k]; b += ents[k]; }
      out[(size_t)M_ * P_ + 0] = a;
      out[(size_t)M_ * P_ + 1] = b;
    }
    return;
  }

  const int wave = tid >> 6, lane = tid & 63;
  const int l15 = lane & 15, quad = lane >> 4;
  const int e = blockIdx.x;
  const int m0 = blockIdx.y * BM;
  const int hz = blockIdx.z * HPZ;
  const int ksz = blockIdx.z * 64;   // w2f kseg base for this z

  const int hq = (wave & 3) * 32;    // GEMM1 wave tile: 32h x 64m
  const int mq = (wave >> 2) * 64;
  const int mt = wave & 3;           // GEMM2 wave tile: 32m x 48p
  const int ph = wave >> 2;

  const u8* w1b = w1q + (size_t)(e * 128 + (hz >> 4) + (hq >> 4)) * TSTRIDE + quad * 128 + l15 * 8;
  const u8* xb  = xq  + (size_t)((m0 >> 4) + (mq >> 4)) * TSTRIDE + quad * 128 + l15 * 8;
  // GEMM2 B base: frag (j,kk) at elem offset j*(256*128) + (ht*16+kk*4)*128
  const __bf16* w2b = w2f + ((size_t)(e * 6 + ph * 3) * 256 + ksz + quad) * 128 + l15 * 8;

  const f32x4 fz = {0.f, 0.f, 0.f, 0.f};
  f32x4 acc2[2][3];
#pragma unroll
  for (int rt = 0; rt < 2; ++rt)
#pragma unroll
    for (int j = 0; j < 3; ++j) acc2[rt][j] = fz;

  for (int ht = 0; ht < NHT; ++ht) {
    const u8* w1h = w1b + (size_t)(ht * 8) * TSTRIDE;
    // hoist bias loads (latency hidden under k-loop)
    f32x4 bv[2];
    {
      const float* b1w = b1 + (size_t)e * H_ + hz + ht * BH + hq;
      bv[0] = *(const f32x4*)(b1w + quad * 4);
      bv[1] = *(const f32x4*)(b1w + 16 + quad * 4);
    }

    f32x4 acc1[2][4];
#pragma unroll
    for (int i = 0; i < 2; ++i)
#pragma unroll
      for (int j = 0; j < 4; ++j) acc1[i][j] = fz;

    // ---- GEMM1: manual 1-kc-deep pipeline, fully unrolled ----
    long a[2][2][2], b[2][2][4];   // [parity][kk][i/j]
#pragma unroll
    for (int kk = 0; kk < 2; ++kk) {
#pragma unroll
      for (int i = 0; i < 2; ++i)
        a[0][kk][i] = *(const long*)(w1h + (size_t)i * TSTRIDE + kk * 512);
#pragma unroll
      for (int j = 0; j < 4; ++j)
        b[0][kk][j] = *(const long*)(xb + (size_t)j * TSTRIDE + kk * 512);
    }
#pragma unroll
    for (int kc = 0; kc < NKC; ++kc) {
      const int cur = kc & 1, nxt = cur ^ 1;
      if (kc + 1 < NKC) {
#pragma unroll
        for (int kk = 0; kk < 2; ++kk) {
#pragma unroll
          for (int i = 0; i < 2; ++i)
            a[nxt][kk][i] = *(const long*)(w1h + (size_t)i * TSTRIDE + (kc + 1) * 1024 + kk * 512);
#pragma unroll
          for (int j = 0; j < 4; ++j)
            b[nxt][kk][j] = *(const long*)(xb + (size_t)j * TSTRIDE + (kc + 1) * 1024 + kk * 512);
        }
      }
#pragma unroll
      for (int kk = 0; kk < 2; ++kk)
#pragma unroll
        for (int i = 0; i < 2; ++i)
#pragma unroll
          for (int j = 0; j < 4; ++j)
            acc1[i][j] = MFMA8(a[cur][kk][i], b[cur][kk][j], acc1[i][j]);
    }

    // bias + gelu (undo W1SCALE) -> Hs[m][h] bf16
#pragma unroll
    for (int i = 0; i < 2; ++i) {
#pragma unroll
      for (int j = 0; j < 4; ++j) {
        bf16x4 hv;
#pragma unroll
        for (int r = 0; r < 4; ++r)
          hv[r] = (__bf16)fast_gelu(acc1[i][j][r] * (1.0f / W1SCALE) + bv[i][r]);
        *(bf16x4*)&Hs[(mq + j * 16 + l15) * HPITCH + hq + i * 16 + quad * 4] = hv;
      }
    }

    // prefetch GEMM2 kk=0 B-frags BEFORE the barrier (L2 latency hides in the wait)
    bf16x8 wb[2][3];
#pragma unroll
    for (int j = 0; j < 3; ++j)
      wb[0][j] = *(const bf16x8*)(w2b + (size_t)j * 32768 + (size_t)(ht * 16) * 128);
    __syncthreads();

    // ---- GEMM2: kk-pipelined ----
#pragma unroll
    for (int kk = 0; kk < 4; ++kk) {
      const int cur = kk & 1, nxt = cur ^ 1;
      if (kk + 1 < 4) {
#pragma unroll
        for (int j = 0; j < 3; ++j)
          wb[nxt][j] = *(const bf16x8*)(w2b + (size_t)j * 32768 + (size_t)(ht * 16 + (kk + 1) * 4) * 128);
      }
      bf16x8 a0 = *(const bf16x8*)&Hs[(mt * 32 + l15) * HPITCH + kk * 32 + quad * 8];
      bf16x8 a1 = *(const bf16x8*)&Hs[(mt * 32 + 16 + l15) * HPITCH + kk * 32 + quad * 8];
#pragma unroll
      for (int j = 0; j < 3; ++j) {
        acc2[0][j] = MFMA16(a0, wb[cur][j], acc2[0][j]);
        acc2[1][j] = MFMA16(a1, wb[cur][j], acc2[1][j]);
      }
    }
    __syncthreads();   // Hs reads done before next ht's gelu rewrites
  }

  // ---- epilogue: out[m,p] += gates[m,e] * (acc + b2 (z==0 only)) ----
#pragma unroll
  for (int rt = 0; rt < 2; ++rt) {
#pragma unroll
    for (int r = 0; r < 4; ++r) {
      int m = m0 + mt * 32 + rt * 16 + quad * 4 + r;
      float g = gates[m * E_ + e];
#pragma unroll
      for (int j = 0; j < 3; ++j) {
        int col = ph * 48 + j * 16 + l15;
        float v = acc2[rt][j][r];
        if (blockIdx.z == 0) v += b2[e * P_ + col];
        atomicAdd(&out[(size_t)m * P_ + col], g * v);
      }
    }
  }
}

extern "C" void kernel_launch(void* const* d_in, const int* in_sizes, int n_in,
                              void* d_out, int out_size, void* d_ws, size_t ws_size,
                              hipStream_t stream) {
  const float* x  = (const float*)d_in[0];
  const float* te = (const float*)d_in[1];
  const float* Wg = (const float*)d_in[2];
  const float* bg = (const float*)d_in[3];
  const float* W1 = (const float*)d_in[4];
  const float* b1 = (const float*)d_in[5];
  const float* W2 = (const float*)d_in[6];
  const float* b2 = (const float*)d_in[7];
  float* out = (float*)d_out;

  char* ws = (char*)d_ws;
  float* gates = (float*)ws;                                  // 65,536 B
  u8* xq       = (u8*)(ws + 65536);                           // 1 MB
  u8* w1q      = (u8*)(ws + 65536 + 1048576);                 // 8 MB
  __bf16* w2f  = (__bf16*)(ws + 65536 + 1048576 + 8388608);   // 3 MB

  hipMemsetAsync(d_out, 0, (size_t)out_size * sizeof(float), stream);
  k_prep_w1<<<256, 256, 0, stream>>>(W1, w1q);
  k_prep_rest<<<1280, 256, 0, stream>>>(x, te, Wg, bg, W2, xq, w2f, gates);
  k_experts<<<dim3(E_, M_ / BM, ZSPLIT + 1), 512, 0, stream>>>(xq, w1q, w2f, b1, b2, gates, out);
}